// Round 5
// baseline (930.827 us; speedup 1.0000x reference)
//
#include <hip/hip_runtime.h>
#include <math.h>

#define NTOK 2048
#define NCH 16

// ---------------- compile-time G(3,0,1) tables ----------------
struct GEnt { unsigned char i, j, k; signed char s; };

constexpr int IDX2MASK[16] = {0,1,2,4,8,3,5,9,6,10,12,7,11,13,14,15};
constexpr int MASK2IDX[16] = {0,1,2,5,3,6,8,11,4,7,9,12,10,13,14,15};

constexpr int rsign(int a, int b){
  int cnt=0;
  for(int i=0;i<4;++i) if((b>>i)&1) for(int j=i+1;j<4;++j) if((a>>j)&1) cnt++;
  return (cnt&1)?-1:1;
}

struct GPTab { GEnt e[192]; };
constexpr GPTab make_gp(){
  GPTab t{}; int n=0;
  for(int ia=0; ia<16; ++ia) for(int ib=0; ib<16; ++ib){
    int a=IDX2MASK[ia], b=IDX2MASK[ib];
    if(a&b&1) continue;                      // e0^2 = 0
    t.e[n].i=(unsigned char)ia; t.e[n].j=(unsigned char)ib;
    t.e[n].k=(unsigned char)MASK2IDX[a^b]; t.e[n].s=(signed char)rsign(a,b);
    ++n;
  }
  return t;
}
static constexpr GPTab GP_TAB = make_gp();

struct JTab { GEnt e[81]; };
constexpr JTab make_join(){
  JTab t{}; int n=0;
  for(int ia=0; ia<16; ++ia) for(int ib=0; ib<16; ++ib){
    int a=IDX2MASK[ia], b=IDX2MASK[ib];
    if((a|b)!=15) continue;                  // dual supports must be disjoint
    int ca=(~a)&15, cb=(~b)&15, k=a&b, ck=(~k)&15;
    int s = rsign(a,ca)*rsign(b,cb)*rsign(ca,cb)*rsign(k,ck);
    t.e[n].i=(unsigned char)ia; t.e[n].j=(unsigned char)ib;
    t.e[n].k=(unsigned char)MASK2IDX[k]; t.e[n].s=(signed char)s;
    ++n;
  }
  return t;
}
static constexpr JTab J_TAB = make_join();

constexpr int INNER[8] = {0,2,3,4,8,9,10,14};   // blades without e0

__device__ __forceinline__ void apply_gp(float* o, const float* a, const float* b){
#pragma unroll
  for(int n=0;n<192;++n){
    const float s = (float)GP_TAB.e[n].s;
    o[GP_TAB.e[n].k] = fmaf(s*a[GP_TAB.e[n].i], b[GP_TAB.e[n].j], o[GP_TAB.e[n].k]);
  }
}
__device__ __forceinline__ void apply_join(float* o, const float* a, const float* b){
#pragma unroll
  for(int n=0;n<81;++n){
    const float s = (float)J_TAB.e[n].s;
    o[J_TAB.e[n].k] = fmaf(s*a[J_TAB.e[n].i], b[J_TAB.e[n].j], o[J_TAB.e[n].k]);
  }
}

// equi_linear for one output channel: 24 FMAs per input channel
// (16 grade-projection terms + 8 left-e0-multiplication terms)
__device__ __forceinline__ void elin_row(float acc[16], const float* xin, const float* w0p){
#pragma unroll
  for(int j=0;j<16;++j) acc[j]=0.0f;
#pragma unroll
  for(int i=0;i<16;++i){
    const float* w = w0p + i*9;
    const float4* xp = (const float4*)(xin + i*16);
    float4 A=xp[0], B=xp[1], Cc=xp[2], D=xp[3];
    float w0=w[0],w1=w[1],w2=w[2],w3=w[3],w4=w[4],w5=w[5],w6=w[6],w7=w[7],w8=w[8];
    acc[0] = fmaf(w0, A.x,  acc[0]);
    acc[1] = fmaf(w1, A.y,  acc[1]);
    acc[2] = fmaf(w1, A.z,  acc[2]);
    acc[3] = fmaf(w1, A.w,  acc[3]);
    acc[4] = fmaf(w1, B.x,  acc[4]);
    acc[5] = fmaf(w2, B.y,  acc[5]);
    acc[6] = fmaf(w2, B.z,  acc[6]);
    acc[7] = fmaf(w2, B.w,  acc[7]);
    acc[8] = fmaf(w2, Cc.x, acc[8]);
    acc[9] = fmaf(w2, Cc.y, acc[9]);
    acc[10]= fmaf(w2, Cc.z, acc[10]);
    acc[11]= fmaf(w3, Cc.w, acc[11]);
    acc[12]= fmaf(w3, D.x,  acc[12]);
    acc[13]= fmaf(w3, D.y,  acc[13]);
    acc[14]= fmaf(w3, D.z,  acc[14]);
    acc[15]= fmaf(w4, D.w,  acc[15]);
    // e0 left-multiplication maps
    acc[1] = fmaf(w5, A.x,  acc[1]);
    acc[5] = fmaf(w6, A.z,  acc[5]);
    acc[6] = fmaf(w6, A.w,  acc[6]);
    acc[7] = fmaf(w6, B.x,  acc[7]);
    acc[11]= fmaf(w7, Cc.x, acc[11]);
    acc[12]= fmaf(w7, Cc.y, acc[12]);
    acc[13]= fmaf(w7, Cc.z, acc[13]);
    acc[15]= fmaf(w8, D.z,  acc[15]);
  }
}

__device__ __forceinline__ float gelu_exact(float x){
  return 0.5f*x*(1.0f+erff(x*0.70710678118654752f));
}

#define WPAD 145          // weight o-stride pad: 145 mod 32 = 17, coprime with 32 -> no bank conflicts
#define TBS  264          // token buf stride (16*16 + 8): staggers token base banks
#define TPB  8            // tokens per workgroup (128 threads), grid 256 fills all CUs

// MODE 0: prologue (embed + W_in, then norm+QKV layer 0)
// MODE 1: Wo+res, norm, MLP(+res), norm, QKV for next layer
// MODE 2: Wo+res, norm, MLP(+res), W_out partial sum
template<int MODE>
__global__ __launch_bounds__(128) void token_kernel(
    const float* __restrict__ points, const float* __restrict__ Win,
    const float* __restrict__ Wo, const float* __restrict__ Wl,
    const float* __restrict__ Wr, const float* __restrict__ Wm,
    const float* __restrict__ Wq, const float* __restrict__ Wk,
    const float* __restrict__ Wv, const float* __restrict__ Wout,
    const float* __restrict__ ATT, float* __restrict__ X,
    float* __restrict__ Qg, float* __restrict__ Kg, float* __restrict__ Vg,
    float* __restrict__ toksum)
{
  __shared__ float wlds[6*16*WPAD];  // slots: 0 Wl, 1 Wr, 2 Wm, 3 Wq, 4 Wk, 5 Wv
  __shared__ float buf[TPB*TBS];
  __shared__ float sred[TPB*16];
  const int tid = threadIdx.x;
  const int t = tid>>4, o = tid&15;
  const int n = blockIdx.x*TPB + t;

  auto stage = [&](float* dst, const float* src){
#pragma unroll
    for(int r=0;r<18;++r){
      int k = tid + r*128;                    // 2304 = 18*128 exact
      dst[(k/144)*WPAD + (k%144)] = src[k];
    }
  };
  if (MODE==0){ stage(wlds+3*16*WPAD, Wq); stage(wlds+4*16*WPAD, Wk); stage(wlds+5*16*WPAD, Wv); }
  if (MODE==1){ stage(wlds+0*16*WPAD, Wl); stage(wlds+1*16*WPAD, Wr); stage(wlds+2*16*WPAD, Wm);
                stage(wlds+3*16*WPAD, Wq); stage(wlds+4*16*WPAD, Wk); stage(wlds+5*16*WPAD, Wv); }
  if (MODE==2){ stage(wlds+0*16*WPAD, Wl); stage(wlds+1*16*WPAD, Wr); stage(wlds+2*16*WPAD, Wm); }

  float* tb = buf + t*TBS;
  float xr[16];

  if (MODE==0){
    float px = points[n*3+0], py = points[n*3+1], pz = points[n*3+2];
    float w3 = Win[o*9+3], w8 = Win[o*9+8];
#pragma unroll
    for(int j=0;j<16;++j) xr[j]=0.0f;
    xr[11]= w3*pz; xr[12]= -w3*py; xr[13]= w3*px; xr[14]= w3; xr[15]= w8;
    float4* xg = (float4*)(X + (size_t)n*256 + o*16);
    xg[0]=make_float4(xr[0],xr[1],xr[2],xr[3]);
    xg[1]=make_float4(xr[4],xr[5],xr[6],xr[7]);
    xg[2]=make_float4(xr[8],xr[9],xr[10],xr[11]);
    xg[3]=make_float4(xr[12],xr[13],xr[14],xr[15]);
  } else {
    const float4* xg = (const float4*)(X + (size_t)n*256 + o*16);
    float4 a=xg[0],b=xg[1],c=xg[2],d=xg[3];
    xr[0]=a.x; xr[1]=a.y; xr[2]=a.z; xr[3]=a.w;
    xr[4]=b.x; xr[5]=b.y; xr[6]=b.z; xr[7]=b.w;
    xr[8]=c.x; xr[9]=c.y; xr[10]=c.z; xr[11]=c.w;
    xr[12]=d.x; xr[13]=d.y; xr[14]=d.z; xr[15]=d.w;
    const float4* ag = (const float4*)(ATT + (size_t)n*256 + o*16);
    float4* bp = (float4*)(tb + o*16);
    bp[0]=ag[0]; bp[1]=ag[1]; bp[2]=ag[2]; bp[3]=ag[3];
    __syncthreads();
    float acc[16];
    elin_row(acc, tb, Wo + o*144);            // Wo from global (L1/L2-hot)
#pragma unroll
    for(int j=0;j<16;++j) xr[j]+=acc[j];
    // --- norm 1 ---
    float s=0;
#pragma unroll
    for(int z=0;z<8;++z){ float v=xr[INNER[z]]; s=fmaf(v,v,s); }
    sred[tid]=s; __syncthreads();
    float tot=0;
#pragma unroll
    for(int c2=0;c2<16;++c2) tot += sred[t*16+c2];
    float f = 1.0f/sqrtf(tot*(1.0f/16.0f)+1e-6f);
    float4* bp2=(float4*)(tb+o*16);
    bp2[0]=make_float4(xr[0]*f,xr[1]*f,xr[2]*f,xr[3]*f);
    bp2[1]=make_float4(xr[4]*f,xr[5]*f,xr[6]*f,xr[7]*f);
    bp2[2]=make_float4(xr[8]*f,xr[9]*f,xr[10]*f,xr[11]*f);
    bp2[3]=make_float4(xr[12]*f,xr[13]*f,xr[14]*f,xr[15]*f);
    __syncthreads();
    // --- MLP ---
    float L[16], R[16];
    elin_row(L, tb, wlds+0*16*WPAD + o*WPAD);
    elin_row(R, tb, wlds+1*16*WPAD + o*WPAD);
    float h[16];
#pragma unroll
    for(int j=0;j<16;++j) h[j]=0.0f;
    if (o<8) apply_gp(h,L,R); else apply_join(h,L,R);
    float gel = gelu_exact(h[0]);
#pragma unroll
    for(int j=0;j<16;++j) h[j]*=gel;
    __syncthreads();                          // Wl/Wr reads of buf done
    float4* bp3=(float4*)(tb+o*16);
    bp3[0]=make_float4(h[0],h[1],h[2],h[3]);
    bp3[1]=make_float4(h[4],h[5],h[6],h[7]);
    bp3[2]=make_float4(h[8],h[9],h[10],h[11]);
    bp3[3]=make_float4(h[12],h[13],h[14],h[15]);
    __syncthreads();
    float mm2[16];
    elin_row(mm2, tb, wlds+2*16*WPAD + o*WPAD);
#pragma unroll
    for(int j=0;j<16;++j) xr[j]+=mm2[j];
    if (MODE==1){
      float4* xs = (float4*)(X + (size_t)n*256 + o*16);
      xs[0]=make_float4(xr[0],xr[1],xr[2],xr[3]);
      xs[1]=make_float4(xr[4],xr[5],xr[6],xr[7]);
      xs[2]=make_float4(xr[8],xr[9],xr[10],xr[11]);
      xs[3]=make_float4(xr[12],xr[13],xr[14],xr[15]);
    }
  }

  if (MODE==2){
    sred[tid] = Wout[o*9]*xr[0];              // only grade-0 weight reaches comp 0
    __syncthreads();
    if (o==0){
      float s2=0;
#pragma unroll
      for(int c2=0;c2<16;++c2) s2+=sred[t*16+c2];
      toksum[n]=s2;
    }
    return;
  }

  // --- norm 2 + QKV (MODE 0 and 1) ---
  {
    float s=0;
#pragma unroll
    for(int z=0;z<8;++z){ float v=xr[INNER[z]]; s=fmaf(v,v,s); }
    sred[tid]=s; __syncthreads();
    float tot=0;
#pragma unroll
    for(int c2=0;c2<16;++c2) tot += sred[t*16+c2];
    float f2 = 1.0f/sqrtf(tot*(1.0f/16.0f)+1e-6f);
    float4* bp4=(float4*)(tb+o*16);
    bp4[0]=make_float4(xr[0]*f2,xr[1]*f2,xr[2]*f2,xr[3]*f2);
    bp4[1]=make_float4(xr[4]*f2,xr[5]*f2,xr[6]*f2,xr[7]*f2);
    bp4[2]=make_float4(xr[8]*f2,xr[9]*f2,xr[10]*f2,xr[11]*f2);
    bp4[3]=make_float4(xr[12]*f2,xr[13]*f2,xr[14]*f2,xr[15]*f2);
    __syncthreads();
    float q_[16],k_[16],v_[16];
    elin_row(q_, tb, wlds+3*16*WPAD+o*WPAD);
    elin_row(k_, tb, wlds+4*16*WPAD+o*WPAD);
    elin_row(v_, tb, wlds+5*16*WPAD+o*WPAD);
    int hh=o>>1, cc=o&1;
    size_t qb = ((size_t)hh*NTOK + n)*16 + cc*8;
    *(float4*)(Qg+qb)   = make_float4(q_[0],q_[2],q_[3],q_[4]);
    *(float4*)(Qg+qb+4) = make_float4(q_[8],q_[9],q_[10],q_[14]);
    *(float4*)(Kg+qb)   = make_float4(k_[0],k_[2],k_[3],k_[4]);
    *(float4*)(Kg+qb+4) = make_float4(k_[8],k_[9],k_[10],k_[14]);
    size_t vb = ((size_t)hh*NTOK + n)*32 + cc*16;
    float4* vp=(float4*)(Vg+vb);
    vp[0]=make_float4(v_[0],v_[1],v_[2],v_[3]);
    vp[1]=make_float4(v_[4],v_[5],v_[6],v_[7]);
    vp[2]=make_float4(v_[8],v_[9],v_[10],v_[11]);
    vp[3]=make_float4(v_[12],v_[13],v_[14],v_[15]);
  }
}

// ---------------- attention: flash-style online softmax ----------------
// WG = 32 queries x 8 key-splits (256 thr), grid = 8 heads x 64 q-blocks = 512
// -> 2048 waves = 8 waves/CU = 2/SIMD.
#define TS 256
__global__ __launch_bounds__(256) void attn_kernel(
    const float* __restrict__ Qg, const float* __restrict__ Kg,
    const float* __restrict__ Vg, float* __restrict__ ATT)
{
  __shared__ float smem[TS*48];               // K tile 4096 + V tile 8192; combine buf 8704 fits
  float* Kl = smem;
  float* Vl = smem + TS*16;
  const int tid=threadIdx.x;
  const int h = blockIdx.x >> 6;
  const int qb = blockIdx.x & 63;
  const int q = tid & 31;
  const int split = tid >> 5;
  const int n = qb*32 + q;

  float qv[16];
  {
    const float4* qp = (const float4*)(Qg + ((size_t)h*NTOK + n)*16);
    float4 q0=qp[0],q1=qp[1],q2=qp[2],q3=qp[3];
    qv[0]=q0.x*0.25f; qv[1]=q0.y*0.25f; qv[2]=q0.z*0.25f; qv[3]=q0.w*0.25f;
    qv[4]=q1.x*0.25f; qv[5]=q1.y*0.25f; qv[6]=q1.z*0.25f; qv[7]=q1.w*0.25f;
    qv[8]=q2.x*0.25f; qv[9]=q2.y*0.25f; qv[10]=q2.z*0.25f; qv[11]=q2.w*0.25f;
    qv[12]=q3.x*0.25f; qv[13]=q3.y*0.25f; qv[14]=q3.z*0.25f; qv[15]=q3.w*0.25f;
  }

  float m = -INFINITY, l = 0.0f;
  float acc[32];
#pragma unroll
  for(int z=0;z<32;++z) acc[z]=0.0f;

  for(int t0=0;t0<NTOK;t0+=TS){
    __syncthreads();
    const float4* ksrc = (const float4*)(Kg + ((size_t)h*NTOK + t0)*16);
    float4* kdst = (float4*)Kl;
#pragma unroll
    for(int r=0;r<4;++r) kdst[tid + r*256] = ksrc[tid + r*256];
    const float4* vsrc = (const float4*)(Vg + ((size_t)h*NTOK + t0)*32);
    float4* vdst=(float4*)Vl;
#pragma unroll
    for(int r=0;r<8;++r) vdst[tid + r*256] = vsrc[tid + r*256];
    __syncthreads();

    const int base = split*32;                // 32 keys per split per tile
#pragma unroll 1
    for(int c0=0;c0<32;c0+=8){
      float d[8];
#pragma unroll
      for(int u=0;u<8;++u){
        const float4* kr = (const float4*)(Kl + (base+c0+u)*16);  // broadcast ds_read_b128 x4
        float4 k0=kr[0], k1=kr[1], k2=kr[2], k3=kr[3];
        float dd;
        dd =      qv[0]*k0.x;
        dd = fmaf(qv[1],k0.y,dd); dd = fmaf(qv[2],k0.z,dd); dd = fmaf(qv[3],k0.w,dd);
        dd = fmaf(qv[4],k1.x,dd); dd = fmaf(qv[5],k1.y,dd); dd = fmaf(qv[6],k1.z,dd);
        dd = fmaf(qv[7],k1.w,dd); dd = fmaf(qv[8],k2.x,dd); dd = fmaf(qv[9],k2.y,dd);
        dd = fmaf(qv[10],k2.z,dd); dd = fmaf(qv[11],k2.w,dd); dd = fmaf(qv[12],k3.x,dd);
        dd = fmaf(qv[13],k3.y,dd); dd = fmaf(qv[14],k3.z,dd); dd = fmaf(qv[15],k3.w,dd);
        d[u]=dd;
      }
      float cmax = d[0];
#pragma unroll
      for(int u=1;u<8;++u) cmax = fmaxf(cmax, d[u]);
      if (cmax > m){
        float corr = __expf(m - cmax);
        m = cmax; l *= corr;
#pragma unroll
        for(int z=0;z<32;++z) acc[z]*=corr;
      }
#pragma unroll
      for(int u=0;u<8;++u){
        float p = __expf(d[u]-m);
        l += p;
        const float4* vr4 = (const float4*)(Vl + (base+c0+u)*32);
#pragma unroll
        for(int zz=0;zz<8;++zz){
          float4 vv = vr4[zz];
          acc[zz*4+0] = fmaf(p, vv.x, acc[zz*4+0]);
          acc[zz*4+1] = fmaf(p, vv.y, acc[zz*4+1]);
          acc[zz*4+2] = fmaf(p, vv.z, acc[zz*4+2]);
          acc[zz*4+3] = fmaf(p, vv.w, acc[zz*4+3]);
        }
      }
    }
  }
  __syncthreads();
  // combine the 8 key-splits per query; each split owns a 4-comp slice
  float* cb = smem + (q*8+split)*34;
  cb[0]=m; cb[1]=l;
#pragma unroll
  for(int z=0;z<32;++z) cb[2+z]=acc[z];
  __syncthreads();
  float M=-INFINITY;
#pragma unroll
  for(int s2=0;s2<8;++s2) M = fmaxf(M, smem[(q*8+s2)*34]);
  float Lt=0.0f, w[8];
#pragma unroll
  for(int s2=0;s2<8;++s2){
    w[s2]=__expf(smem[(q*8+s2)*34]-M);
    Lt = fmaf(smem[(q*8+s2)*34+1], w[s2], Lt);
  }
  float inv = 1.0f/Lt;
  float o4[4];
#pragma unroll
  for(int z=0;z<4;++z){
    float v=0.0f;
#pragma unroll
    for(int s2=0;s2<8;++s2) v = fmaf(smem[(q*8+s2)*34+2+split*4+z], w[s2], v);
    o4[z]=v*inv;
  }
  // acc slice [split*4, split*4+4): sub-channel cc = split>>2, comp16 = (split&3)*4
  size_t ob = (size_t)n*256 + (size_t)(2*h + (split>>2))*16 + (split&3)*4;
  *(float4*)(ATT+ob) = make_float4(o4[0],o4[1],o4[2],o4[3]);
}

__global__ __launch_bounds__(256) void reduce_kernel(const float* __restrict__ tok, float* __restrict__ out){
  int tid=threadIdx.x;
  float s=0;
  for(int i=tid;i<NTOK;i+=256) s+=tok[i];
#pragma unroll
  for(int off=32;off>0;off>>=1) s += __shfl_down(s,off);
  __shared__ float red[4];
  if((tid&63)==0) red[tid>>6]=s;
  __syncthreads();
  if(tid==0) out[0]=(red[0]+red[1]+red[2]+red[3])*(1.0f/2048.0f);
}

extern "C" void kernel_launch(void* const* d_in, const int* in_sizes, int n_in,
                              void* d_out, int out_size, void* d_ws, size_t ws_size,
                              hipStream_t stream){
  const float* points=(const float*)d_in[0];
  const float* Win=(const float*)d_in[1];
  const float* Wq=(const float*)d_in[2];
  const float* Wk=(const float*)d_in[3];
  const float* Wv=(const float*)d_in[4];
  const float* Wo=(const float*)d_in[5];
  const float* Wl=(const float*)d_in[6];
  const float* Wr=(const float*)d_in[7];
  const float* Wm=(const float*)d_in[8];
  const float* Wout=(const float*)d_in[9];
  float* ws=(float*)d_ws;
  float* X   = ws;
  float* ATT = ws + 524288;
  float* Qg  = ws + 1048576;
  float* Kg  = ws + 1310720;
  float* Vg  = ws + 1572864;
  float* tok = ws + 2097152;
  float* out=(float*)d_out;

  token_kernel<0><<<256,128,0,stream>>>(points,Win,nullptr,nullptr,nullptr,nullptr,
                                        Wq,Wk,Wv,nullptr,nullptr,X,Qg,Kg,Vg,nullptr);
  for(int l=0;l<10;++l){
    attn_kernel<<<512,256,0,stream>>>(Qg,Kg,Vg,ATT);
    if(l<9){
      token_kernel<1><<<256,128,0,stream>>>(nullptr,nullptr,
          Wo+l*2304,Wl+l*2304,Wr+l*2304,Wm+l*2304,
          Wq+(l+1)*2304,Wk+(l+1)*2304,Wv+(l+1)*2304,nullptr,
          ATT,X,Qg,Kg,Vg,nullptr);
    } else {
      token_kernel<2><<<256,128,0,stream>>>(nullptr,nullptr,
          Wo+l*2304,Wl+l*2304,Wr+l*2304,Wm+l*2304,
          nullptr,nullptr,nullptr,Wout,
          ATT,X,nullptr,nullptr,nullptr,tok);
    }
  }
  reduce_kernel<<<1,256,0,stream>>>(tok,out);
}